// Round 1
// baseline (223.610 us; speedup 1.0000x reference)
//
#include <hip/hip_runtime.h>
#include <math.h>

#define EPSF 1e-6f
constexpr int Bn  = 32;
constexpr int CLS = 16;
constexpr int DST = 8;
constexpr int Cc  = 64, Hh = 16, Wd = 16;
constexpr int CHW  = Cc * Hh * Wd;   // 16384
constexpr int CHW2 = 2 * CHW;        // 32768
constexpr int CHW4 = 4 * CHW;        // 65536

// stable log-sigmoid: -log(1+exp(-x)) = min(x,0) - log1p(exp(-|x|))
__device__ __forceinline__ float log_sigmoid(float x) {
    float ax = fabsf(x);
    return fminf(x, 0.0f) - log1pf(expf(-ax));
}

// ---------------------------------------------------------------------------
// Kernel A: per-class segment sums -> xle_out, xy_out. Also zeroes le_norm.
// Thread e in [0, 2*CHW). Accumulation order over b ascending == segment_sum.
// ---------------------------------------------------------------------------
__global__ void kA(const float* __restrict__ x, const int* __restrict__ labels,
                   const float* __restrict__ X_LEs, const float* __restrict__ X_LEs_xy,
                   const float* __restrict__ X_weights,
                   float* __restrict__ xle_out, float* __restrict__ xy_out,
                   float* __restrict__ le_norm)
{
    const int e = blockIdx.x * blockDim.x + threadIdx.x;   // [0, CHW2)
    __shared__ int lab_sh[Bn];
    if (threadIdx.x < Bn) lab_sh[threadIdx.x] = labels[threadIdx.x];
    __syncthreads();

    if (e < DST * CLS) le_norm[e] = 0.0f;   // zero the 128-cell accumulator

    float acc_tm[CLS], acc_xy[CLS], cnt[CLS];
#pragma unroll
    for (int c = 0; c < CLS; ++c) { acc_tm[c] = 0.f; acc_xy[c] = 0.f; cnt[c] = 0.f; }

    for (int b = 0; b < Bn; ++b) {
        const int lab = lab_sh[b];
        const float xt  = x[b * CHW4 + e];          // x_tm flat element e
        const float xxy = x[b * CHW4 + CHW2 + e];   // x_xy flat element e
#pragma unroll
        for (int c = 0; c < CLS; ++c) {
            const bool m = (lab == c);
            acc_tm[c] += m ? xt  : 0.0f;
            acc_xy[c] += m ? xxy : 0.0f;
            cnt[c]    += m ? 1.0f : 0.0f;
        }
    }

#pragma unroll
    for (int c = 0; c < CLS; ++c) {
        const float xw = X_weights[c] + cnt[c];
        xle_out[c * CHW2 + e] = (X_LEs[c * CHW2 + e]    + acc_tm[c]) / xw;
        xy_out [c * CHW2 + e] = (X_LEs_xy[c * CHW2 + e] + acc_xy[c]) / xw;
    }
}

// ---------------------------------------------------------------------------
// Kernel B: per (c, e): means_theta, log(means_mag+eps); le_norm[d][c] partials.
// 64 blocks per class, 256 threads each.
// ---------------------------------------------------------------------------
__global__ void kB(const float* __restrict__ xle_out, const float* __restrict__ miu,
                   const float* __restrict__ sigmas, const float* __restrict__ tao,
                   const float* __restrict__ w1,
                   float* __restrict__ means_theta, float* __restrict__ lmm_out,
                   float* __restrict__ le_norm)
{
    const int c = blockIdx.x >> 6;
    const int e = ((blockIdx.x & 63) * blockDim.x) + threadIdx.x;   // [0, CHW)

    const float sig    = sigmas[c];
    const float sig_sq = sig * sig;

    float w1sqv[DST];
    float ssum = 0.f;
#pragma unroll
    for (int d = 0; d < DST; ++d) { const float t = w1[d]; w1sqv[d] = t * t; ssum += t * t; }

    const float xle0 = xle_out[c * CHW2 + e];
    const float xle1 = xle_out[c * CHW2 + CHW + e];   // mag
    const float ls0  = log_sigmoid(xle0);
    const float ls1  = log_sigmoid(xle1);
    const float ls1e = log_sigmoid(xle1 + EPSF);

    float mt = 0.f, mm = 0.f;
    float ln_d[DST];

#pragma unroll
    for (int d = 0; d < DST; ++d) {
        const float ta     = tao[d];
        const float tao_sq = ta * ta;
        const float den    = sig_sq + tao_sq;
        const float a      = tao_sq / den;
        const float b      = sig_sq / den;
        const float wn     = w1sqv[d] / ssum;

        const float m0 = miu[d * CHW2 + e];
        const float m1 = miu[d * CHW2 + CHW + e];
        const float lm0  = log_sigmoid(m0);
        const float lm1  = log_sigmoid(m1);
        const float lm1e = log_sigmoid(m1 + EPSF);

        mt += (xle1 * a + m0 * b) * wn;
        mm += expf((a * ls1e + b * lm1e) * wn);

        const float d0 = ls0 - lm0, d1 = ls1 - lm1;
        ln_d[d] = d0 * d0 + d1 * d1;
    }

    means_theta[c * CHW + e] = mt;
    lmm_out   [c * CHW + e] = logf(mm + EPSF);

    // wave-level reduction of le_norm partials, one atomic per wave per d
#pragma unroll
    for (int d = 0; d < DST; ++d) {
        float v = ln_d[d];
        v += __shfl_down(v, 32);
        v += __shfl_down(v, 16);
        v += __shfl_down(v, 8);
        v += __shfl_down(v, 4);
        v += __shfl_down(v, 2);
        v += __shfl_down(v, 1);
        if ((threadIdx.x & 63) == 0) atomicAdd(&le_norm[d * CLS + c], v);
    }
}

// ---------------------------------------------------------------------------
// Kernel C: loss[d] = mean_c( term1 * (term2 + term3) ). One block, 128 thr.
// ---------------------------------------------------------------------------
__global__ void kC(const int* __restrict__ labels, const float* __restrict__ X_weights,
                   const float* __restrict__ sigmas, const float* __restrict__ tao,
                   const float* __restrict__ le_norm, float* __restrict__ loss_out)
{
    const int t = threadIdx.x;        // [0,128)
    const int d = t >> 4;
    const int c = t & 15;

    float cnt = 0.f;
    for (int b = 0; b < Bn; ++b) cnt += (labels[b] == c) ? 1.f : 0.f;
    const float xw = X_weights[c] + cnt;

    const float sig = sigmas[c], ssq = sig * sig;
    const float ta  = tao[d],    tsq = ta * ta;
    const float den = tsq + ssq;

    const float term1 = ssq / (den * den);
    const float term2 = ssq * le_norm[d * CLS + c];
    const float term3 = (2.0f * (float)CHW) * (tsq * tsq - ssq * ssq) / xw;

    float v = term1 * (term2 + term3);
    // sum across the 16-lane class group (lanes d*16 .. d*16+15 within a wave)
    v += __shfl_xor(v, 8);
    v += __shfl_xor(v, 4);
    v += __shfl_xor(v, 2);
    v += __shfl_xor(v, 1);
    if (c == 0) loss_out[d] = v * (1.0f / 16.0f);
}

// ---------------------------------------------------------------------------
// Kernel D: dist over (c,b,e), min over c -> out[b*CHW+e].
// ---------------------------------------------------------------------------
__global__ void kD(const float* __restrict__ x, const float* __restrict__ weight,
                   const float* __restrict__ means_theta, const float* __restrict__ lmm,
                   const float* __restrict__ xy_out, float* __restrict__ out)
{
    const int idx = blockIdx.x * blockDim.x + threadIdx.x;  // [0, Bn*CHW)
    const int b = idx >> 14;          // / CHW
    const int e = idx & (CHW - 1);

    const float w0 = weight[0], w1w = weight[1], w2 = weight[2];
    const float w0sq = w0 * w0, w1sq = w1w * w1w, w2sq = w2 * w2;

    const float* xb = x + b * CHW4;
    const float xt0 = xb[e];
    const float xt1 = xb[CHW + e];
    const float xx0 = xb[CHW2 + e];
    const float xx1 = xb[CHW2 + CHW + e];
    const float lx  = logf(xt1);

    float m = __builtin_inff();
#pragma unroll
    for (int c = 0; c < CLS; ++c) {
        const float mtv = means_theta[c * CHW + e];
        const float lmv = lmm[c * CHW + e];
        const float y0  = xy_out[c * CHW2 + e];
        const float y1  = xy_out[c * CHW2 + CHW + e];
        const float dr  = fabsf(xt0 - mtv);
        const float da  = fabsf(lx - lmv);
        const float d0  = xx0 - y0, d1 = xx1 - y1;
        const float dist = w0sq * dr + w1sq * da + w2sq * (d0 * d0 + d1 * d1);
        m = fminf(m, dist);
    }
    out[idx] = m;
}

// ---------------------------------------------------------------------------
extern "C" void kernel_launch(void* const* d_in, const int* in_sizes, int n_in,
                              void* d_out, int out_size, void* d_ws, size_t ws_size,
                              hipStream_t stream)
{
    const float* x         = (const float*)d_in[0];
    const int*   labels    = (const int*)  d_in[1];
    const float* X_LEs     = (const float*)d_in[2];
    const float* X_LEs_xy  = (const float*)d_in[3];
    const float* X_weights = (const float*)d_in[4];
    const float* sigmas    = (const float*)d_in[5];
    const float* w1        = (const float*)d_in[6];
    const float* miu       = (const float*)d_in[7];
    const float* tao       = (const float*)d_in[8];
    const float* weight    = (const float*)d_in[9];

    float* ws          = (float*)d_ws;
    float* xle_out     = ws;                      // 524288 floats
    float* xy_out      = ws + 524288;             // 524288
    float* means_theta = ws + 1048576;            // 262144
    float* lmm         = ws + 1310720;            // 262144
    float* le_norm     = ws + 1572864;            // 128

    float* out  = (float*)d_out;       // 524288
    float* loss = out + Bn * CHW;      // 8

    hipLaunchKernelGGL(kA, dim3(CHW2 / 256), dim3(256), 0, stream,
                       x, labels, X_LEs, X_LEs_xy, X_weights, xle_out, xy_out, le_norm);
    hipLaunchKernelGGL(kB, dim3(CLS * 64), dim3(256), 0, stream,
                       xle_out, miu, sigmas, tao, w1, means_theta, lmm, le_norm);
    hipLaunchKernelGGL(kC, dim3(1), dim3(128), 0, stream,
                       labels, X_weights, sigmas, tao, le_norm, loss);
    hipLaunchKernelGGL(kD, dim3(Bn * CHW / 256), dim3(256), 0, stream,
                       x, weight, means_theta, lmm, xy_out, out);
}

// Round 2
// 216.253 us; speedup vs baseline: 1.0340x; 1.0340x over previous
//
#include <hip/hip_runtime.h>
#include <math.h>

#define EPSF 1e-6f
constexpr int Bn  = 32;
constexpr int CLS = 16;
constexpr int DST = 8;
constexpr int Cc  = 64, Hh = 16, Wd = 16;
constexpr int CHW  = Cc * Hh * Wd;   // 16384
constexpr int CHW2 = 2 * CHW;        // 32768
constexpr int CHW4 = 4 * CHW;        // 65536

// fast log-sigmoid: -log(1+exp(-x)) = min(x,0) - log(1+exp(-|x|))
// uses v_exp_f32 / v_log_f32 (rel err ~2^-21) — well inside tolerance
__device__ __forceinline__ float fls(float x) {
    float t = __expf(-fabsf(x));
    return fminf(x, 0.0f) - __logf(1.0f + t);
}

// ---------------------------------------------------------------------------
// k1: blocks [0,128):  kA — per-class segment sums -> xle_out, xy_out,
//                      zero le_norm.
//     blocks [128,640): lm-precompute — per (d,e): log_sigmoid of miu.
// ---------------------------------------------------------------------------
__global__ void k1(const float* __restrict__ x, const int* __restrict__ labels,
                   const float* __restrict__ X_LEs, const float* __restrict__ X_LEs_xy,
                   const float* __restrict__ X_weights, const float* __restrict__ miu,
                   float* __restrict__ xle_out, float* __restrict__ xy_out,
                   float* __restrict__ le_norm,
                   float* __restrict__ lm0a, float* __restrict__ lm1a,
                   float* __restrict__ lm1ea)
{
    if (blockIdx.x >= 128) {
        // ---- lm precompute path: idx over [0, DST*CHW) ----
        const int idx = (blockIdx.x - 128) * blockDim.x + threadIdx.x;
        const int d = idx >> 14;           // / CHW
        const int e = idx & (CHW - 1);
        const float m0 = miu[d * CHW2 + e];
        const float m1 = miu[d * CHW2 + CHW + e];
        lm0a [idx] = fls(m0);
        lm1a [idx] = fls(m1);
        lm1ea[idx] = fls(m1 + EPSF);
        return;
    }

    // ---- kA path: e over [0, CHW2) ----
    const int e = blockIdx.x * blockDim.x + threadIdx.x;
    __shared__ int lab_sh[Bn];
    if (threadIdx.x < Bn) lab_sh[threadIdx.x] = labels[threadIdx.x];
    __syncthreads();

    if (e < DST * CLS) le_norm[e] = 0.0f;

    float acc_tm[CLS], acc_xy[CLS], cnt[CLS];
#pragma unroll
    for (int c = 0; c < CLS; ++c) { acc_tm[c] = 0.f; acc_xy[c] = 0.f; cnt[c] = 0.f; }

    for (int b = 0; b < Bn; ++b) {
        const int lab = lab_sh[b];
        const float xt  = x[b * CHW4 + e];
        const float xxy = x[b * CHW4 + CHW2 + e];
#pragma unroll
        for (int c = 0; c < CLS; ++c) {
            const bool m = (lab == c);
            acc_tm[c] += m ? xt  : 0.0f;
            acc_xy[c] += m ? xxy : 0.0f;
            cnt[c]    += m ? 1.0f : 0.0f;
        }
    }

#pragma unroll
    for (int c = 0; c < CLS; ++c) {
        const float xw = X_weights[c] + cnt[c];
        xle_out[c * CHW2 + e] = (X_LEs[c * CHW2 + e]    + acc_tm[c]) / xw;
        xy_out [c * CHW2 + e] = (X_LEs_xy[c * CHW2 + e] + acc_xy[c]) / xw;
    }
}

// ---------------------------------------------------------------------------
// k2 (kB): per (c,e): means_theta, log(means_mag+eps); le_norm partials.
// miu log-sigmoids come precomputed from k1 (L2-resident).
// ---------------------------------------------------------------------------
__global__ void k2(const float* __restrict__ xle_out, const float* __restrict__ miu,
                   const float* __restrict__ sigmas, const float* __restrict__ tao,
                   const float* __restrict__ w1,
                   const float* __restrict__ lm0a, const float* __restrict__ lm1a,
                   const float* __restrict__ lm1ea,
                   float* __restrict__ means_theta, float* __restrict__ lmm_out,
                   float* __restrict__ le_norm)
{
    const int c = blockIdx.x >> 6;
    const int e = ((blockIdx.x & 63) * blockDim.x) + threadIdx.x;   // [0, CHW)

    const float sig    = sigmas[c];
    const float sig_sq = sig * sig;

    float w1sqv[DST];
    float ssum = 0.f;
#pragma unroll
    for (int d = 0; d < DST; ++d) { const float t = w1[d]; w1sqv[d] = t * t; ssum += t * t; }
    const float ssum_r = 1.0f / ssum;

    const float xle0 = xle_out[c * CHW2 + e];
    const float xle1 = xle_out[c * CHW2 + CHW + e];   // mag
    const float ls0  = fls(xle0);
    const float ls1  = fls(xle1);
    const float ls1e = fls(xle1 + EPSF);

    float mt = 0.f, mm = 0.f;
    float ln_d[DST];

#pragma unroll
    for (int d = 0; d < DST; ++d) {
        const float ta     = tao[d];
        const float tao_sq = ta * ta;
        const float den_r  = 1.0f / (sig_sq + tao_sq);
        const float a      = tao_sq * den_r;
        const float b      = sig_sq * den_r;
        const float wn     = w1sqv[d] * ssum_r;

        const float m0   = miu[d * CHW2 + e];
        const float lm0  = lm0a [d * CHW + e];
        const float lm1  = lm1a [d * CHW + e];
        const float lm1e = lm1ea[d * CHW + e];

        mt += (xle1 * a + m0 * b) * wn;
        mm += __expf((a * ls1e + b * lm1e) * wn);

        const float d0 = ls0 - lm0, d1 = ls1 - lm1;
        ln_d[d] = d0 * d0 + d1 * d1;
    }

    means_theta[c * CHW + e] = mt;
    lmm_out   [c * CHW + e] = __logf(mm + EPSF);

#pragma unroll
    for (int d = 0; d < DST; ++d) {
        float v = ln_d[d];
        v += __shfl_down(v, 32);
        v += __shfl_down(v, 16);
        v += __shfl_down(v, 8);
        v += __shfl_down(v, 4);
        v += __shfl_down(v, 2);
        v += __shfl_down(v, 1);
        if ((threadIdx.x & 63) == 0) atomicAdd(&le_norm[d * CLS + c], v);
    }
}

// ---------------------------------------------------------------------------
// k3: blocks [0,2048): kD — dist over (c,b,e), min over c.
//     block 2048:      kC — loss[d] (128 active threads).
// ---------------------------------------------------------------------------
__global__ void k3(const float* __restrict__ x, const float* __restrict__ weight,
                   const float* __restrict__ means_theta, const float* __restrict__ lmm,
                   const float* __restrict__ xy_out,
                   const int* __restrict__ labels, const float* __restrict__ X_weights,
                   const float* __restrict__ sigmas, const float* __restrict__ tao,
                   const float* __restrict__ le_norm,
                   float* __restrict__ out, float* __restrict__ loss_out)
{
    if (blockIdx.x == 2048) {
        const int t = threadIdx.x;
        if (t >= 128) return;
        const int d = t >> 4;
        const int c = t & 15;

        float cnt = 0.f;
        for (int b = 0; b < Bn; ++b) cnt += (labels[b] == c) ? 1.f : 0.f;
        const float xw = X_weights[c] + cnt;

        const float sig = sigmas[c], ssq = sig * sig;
        const float ta  = tao[d],    tsq = ta * ta;
        const float den = tsq + ssq;

        const float term1 = ssq / (den * den);
        const float term2 = ssq * le_norm[d * CLS + c];
        const float term3 = (2.0f * (float)CHW) * (tsq * tsq - ssq * ssq) / xw;

        float v = term1 * (term2 + term3);
        v += __shfl_xor(v, 8);
        v += __shfl_xor(v, 4);
        v += __shfl_xor(v, 2);
        v += __shfl_xor(v, 1);
        if (c == 0) loss_out[d] = v * (1.0f / 16.0f);
        return;
    }

    const int idx = blockIdx.x * blockDim.x + threadIdx.x;  // [0, Bn*CHW)
    const int b = idx >> 14;
    const int e = idx & (CHW - 1);

    const float w0 = weight[0], w1w = weight[1], w2 = weight[2];
    const float w0sq = w0 * w0, w1sq = w1w * w1w, w2sq = w2 * w2;

    const float* xb = x + b * CHW4;
    const float xt0 = xb[e];
    const float xt1 = xb[CHW + e];
    const float xx0 = xb[CHW2 + e];
    const float xx1 = xb[CHW2 + CHW + e];
    const float lx  = __logf(xt1);

    float m = __builtin_inff();
#pragma unroll
    for (int c = 0; c < CLS; ++c) {
        const float mtv = means_theta[c * CHW + e];
        const float lmv = lmm[c * CHW + e];
        const float y0  = xy_out[c * CHW2 + e];
        const float y1  = xy_out[c * CHW2 + CHW + e];
        const float dr  = fabsf(xt0 - mtv);
        const float da  = fabsf(lx - lmv);
        const float d0  = xx0 - y0, d1 = xx1 - y1;
        const float dist = w0sq * dr + w1sq * da + w2sq * (d0 * d0 + d1 * d1);
        m = fminf(m, dist);
    }
    out[idx] = m;
}

// ---------------------------------------------------------------------------
extern "C" void kernel_launch(void* const* d_in, const int* in_sizes, int n_in,
                              void* d_out, int out_size, void* d_ws, size_t ws_size,
                              hipStream_t stream)
{
    const float* x         = (const float*)d_in[0];
    const int*   labels    = (const int*)  d_in[1];
    const float* X_LEs     = (const float*)d_in[2];
    const float* X_LEs_xy  = (const float*)d_in[3];
    const float* X_weights = (const float*)d_in[4];
    const float* sigmas    = (const float*)d_in[5];
    const float* w1        = (const float*)d_in[6];
    const float* miu       = (const float*)d_in[7];
    const float* tao       = (const float*)d_in[8];
    const float* weight    = (const float*)d_in[9];

    float* ws          = (float*)d_ws;
    float* xle_out     = ws;                      // 524288 floats
    float* xy_out      = ws + 524288;             // 524288
    float* means_theta = ws + 1048576;            // 262144
    float* lmm         = ws + 1310720;            // 262144
    float* le_norm     = ws + 1572864;            // 128
    float* lm0a        = ws + 1572992;            // 131072
    float* lm1a        = ws + 1704064;            // 131072
    float* lm1ea       = ws + 1835136;            // 131072 -> total 1966208 floats (7.87 MB)

    float* out  = (float*)d_out;       // 524288
    float* loss = out + Bn * CHW;      // 8

    hipLaunchKernelGGL(k1, dim3(128 + DST * CHW / 256), dim3(256), 0, stream,
                       x, labels, X_LEs, X_LEs_xy, X_weights, miu,
                       xle_out, xy_out, le_norm, lm0a, lm1a, lm1ea);
    hipLaunchKernelGGL(k2, dim3(CLS * 64), dim3(256), 0, stream,
                       xle_out, miu, sigmas, tao, w1, lm0a, lm1a, lm1ea,
                       means_theta, lmm, le_norm);
    hipLaunchKernelGGL(k3, dim3(Bn * CHW / 256 + 1), dim3(256), 0, stream,
                       x, weight, means_theta, lmm, xy_out,
                       labels, X_weights, sigmas, tao, le_norm,
                       out, loss);
}

// Round 3
// 96.932 us; speedup vs baseline: 2.3069x; 2.2310x over previous
//
#include <hip/hip_runtime.h>
#include <math.h>

#define EPSF 1e-6f
constexpr int Bn  = 32;
constexpr int CLS = 16;
constexpr int DST = 8;
constexpr int Cc  = 64, Hh = 16, Wd = 16;
constexpr int CHW  = Cc * Hh * Wd;   // 16384
constexpr int CHW2 = 2 * CHW;        // 32768
constexpr int CHW4 = 4 * CHW;        // 65536
constexpr int KCHUNK = 64;           // k2 chunks per class

// fast log-sigmoid: -log(1+exp(-x)) = min(x,0) - log(1+exp(-|x|))
__device__ __forceinline__ float fls(float x) {
    float t = __expf(-fabsf(x));
    return fminf(x, 0.0f) - __logf(1.0f + t);
}

// ---------------------------------------------------------------------------
// k1: blocks [0,2048):    kA — (class, e-chunk) segment sums -> xle_out, xy_out.
//                         c is block-uniform => label match branch is uniform,
//                         non-matching batches are skipped entirely.
//     blocks [2048,2560): lm-precompute — per (d,e): log_sigmoid of miu.
// ---------------------------------------------------------------------------
__global__ void k1(const float* __restrict__ x, const int* __restrict__ labels,
                   const float* __restrict__ X_LEs, const float* __restrict__ X_LEs_xy,
                   const float* __restrict__ X_weights, const float* __restrict__ miu,
                   float* __restrict__ xle_out, float* __restrict__ xy_out,
                   float* __restrict__ lm0a, float* __restrict__ lm1a,
                   float* __restrict__ lm1ea)
{
    if (blockIdx.x >= 2048) {
        const int idx = (blockIdx.x - 2048) * blockDim.x + threadIdx.x; // [0, DST*CHW)
        const int d = idx >> 14;
        const int e = idx & (CHW - 1);
        const float m0 = miu[d * CHW2 + e];
        const float m1 = miu[d * CHW2 + CHW + e];
        lm0a [idx] = fls(m0);
        lm1a [idx] = fls(m1);
        lm1ea[idx] = fls(m1 + EPSF);
        return;
    }

    // ---- kA path: c = class, e over [0, CHW2) ----
    const int c = blockIdx.x >> 7;                       // [0,16)
    const int e = (blockIdx.x & 127) * blockDim.x + threadIdx.x;  // [0, CHW2)

    __shared__ int lab_sh[Bn];
    if (threadIdx.x < Bn) lab_sh[threadIdx.x] = labels[threadIdx.x];
    __syncthreads();

    float acc_tm = 0.f, acc_xy = 0.f, cnt = 0.f;
    for (int b = 0; b < Bn; ++b) {
        if (lab_sh[b] == c) {          // block-uniform branch: skip loads entirely
            acc_tm += x[b * CHW4 + e];
            acc_xy += x[b * CHW4 + CHW2 + e];
            cnt    += 1.0f;
        }
    }

    const float xw_r = 1.0f / (X_weights[c] + cnt);
    xle_out[c * CHW2 + e] = (X_LEs[c * CHW2 + e]    + acc_tm) * xw_r
                            * (X_weights[c] + cnt) * xw_r;   // placeholder? no
    // NOTE: keep exact divide semantics (match reference):
    xle_out[c * CHW2 + e] = (X_LEs[c * CHW2 + e]    + acc_tm) / (X_weights[c] + cnt);
    xy_out [c * CHW2 + e] = (X_LEs_xy[c * CHW2 + e] + acc_xy) / (X_weights[c] + cnt);
}

// ---------------------------------------------------------------------------
// k2: per (c,e): means_theta, log(means_mag+eps); le_norm partials -> block
// reduce in LDS, write 8 unique partials per block. NO atomics.
// ---------------------------------------------------------------------------
__global__ void k2(const float* __restrict__ xle_out, const float* __restrict__ miu,
                   const float* __restrict__ sigmas, const float* __restrict__ tao,
                   const float* __restrict__ w1,
                   const float* __restrict__ lm0a, const float* __restrict__ lm1a,
                   const float* __restrict__ lm1ea,
                   float* __restrict__ means_theta, float* __restrict__ lmm_out,
                   float* __restrict__ partials)
{
    const int c     = blockIdx.x >> 6;
    const int chunk = blockIdx.x & 63;
    const int e     = chunk * blockDim.x + threadIdx.x;   // [0, CHW)

    const float sig    = sigmas[c];
    const float sig_sq = sig * sig;

    float w1sqv[DST];
    float ssum = 0.f;
#pragma unroll
    for (int d = 0; d < DST; ++d) { const float t = w1[d]; w1sqv[d] = t * t; ssum += t * t; }
    const float ssum_r = 1.0f / ssum;

    const float xle0 = xle_out[c * CHW2 + e];
    const float xle1 = xle_out[c * CHW2 + CHW + e];   // mag
    const float ls0  = fls(xle0);
    const float ls1  = fls(xle1);
    const float ls1e = fls(xle1 + EPSF);

    float mt = 0.f, mm = 0.f;
    float ln_d[DST];

#pragma unroll
    for (int d = 0; d < DST; ++d) {
        const float ta     = tao[d];
        const float tao_sq = ta * ta;
        const float den_r  = 1.0f / (sig_sq + tao_sq);
        const float a      = tao_sq * den_r;
        const float b      = sig_sq * den_r;
        const float wn     = w1sqv[d] * ssum_r;

        const float m0   = miu[d * CHW2 + e];
        const float lm0  = lm0a [d * CHW + e];
        const float lm1  = lm1a [d * CHW + e];
        const float lm1e = lm1ea[d * CHW + e];

        mt += (xle1 * a + m0 * b) * wn;
        mm += __expf((a * ls1e + b * lm1e) * wn);

        const float d0 = ls0 - lm0, d1 = ls1 - lm1;
        ln_d[d] = d0 * d0 + d1 * d1;
    }

    means_theta[c * CHW + e] = mt;
    lmm_out    [c * CHW + e] = __logf(mm + EPSF);

    // wave-level shuffle reduce, then cross-wave LDS reduce, one store per d.
    __shared__ float sh[4][DST];
    const int wave = threadIdx.x >> 6;
    const int lane = threadIdx.x & 63;
#pragma unroll
    for (int d = 0; d < DST; ++d) {
        float v = ln_d[d];
        v += __shfl_down(v, 32);
        v += __shfl_down(v, 16);
        v += __shfl_down(v, 8);
        v += __shfl_down(v, 4);
        v += __shfl_down(v, 2);
        v += __shfl_down(v, 1);
        if (lane == 0) sh[wave][d] = v;
    }
    __syncthreads();
    if (threadIdx.x < DST) {
        const int d = threadIdx.x;
        const float s = sh[0][d] + sh[1][d] + sh[2][d] + sh[3][d];
        partials[(d * CLS + c) * KCHUNK + chunk] = s;
    }
}

// ---------------------------------------------------------------------------
// k3: blocks [0,2048): kD — dist over (c,b,e), min over c.
//     block 2048:      kC — loss[d], second-stage reduce of partials.
// ---------------------------------------------------------------------------
__global__ void k3(const float* __restrict__ x, const float* __restrict__ weight,
                   const float* __restrict__ means_theta, const float* __restrict__ lmm,
                   const float* __restrict__ xy_out,
                   const int* __restrict__ labels, const float* __restrict__ X_weights,
                   const float* __restrict__ sigmas, const float* __restrict__ tao,
                   const float* __restrict__ partials,
                   float* __restrict__ out, float* __restrict__ loss_out)
{
    if (blockIdx.x == 2048) {
        const int t = threadIdx.x;
        if (t >= 128) return;
        const int d = t >> 4;
        const int c = t & 15;

        // second-stage le_norm reduction: 64 contiguous partials per (d,c)
        const float* p = partials + (d * CLS + c) * KCHUNK;
        float le = 0.f;
#pragma unroll
        for (int k = 0; k < KCHUNK; ++k) le += p[k];

        float cnt = 0.f;
        for (int b = 0; b < Bn; ++b) cnt += (labels[b] == c) ? 1.f : 0.f;
        const float xw = X_weights[c] + cnt;

        const float sig = sigmas[c], ssq = sig * sig;
        const float ta  = tao[d],    tsq = ta * ta;
        const float den = tsq + ssq;

        const float term1 = ssq / (den * den);
        const float term2 = ssq * le;
        const float term3 = (2.0f * (float)CHW) * (tsq * tsq - ssq * ssq) / xw;

        float v = term1 * (term2 + term3);
        v += __shfl_xor(v, 8);
        v += __shfl_xor(v, 4);
        v += __shfl_xor(v, 2);
        v += __shfl_xor(v, 1);
        if (c == 0) loss_out[d] = v * (1.0f / 16.0f);
        return;
    }

    const int idx = blockIdx.x * blockDim.x + threadIdx.x;  // [0, Bn*CHW)
    const int b = idx >> 14;
    const int e = idx & (CHW - 1);

    const float w0 = weight[0], w1w = weight[1], w2 = weight[2];
    const float w0sq = w0 * w0, w1sq = w1w * w1w, w2sq = w2 * w2;

    const float* xb = x + b * CHW4;
    const float xt0 = xb[e];
    const float xt1 = xb[CHW + e];
    const float xx0 = xb[CHW2 + e];
    const float xx1 = xb[CHW2 + CHW + e];
    const float lx  = __logf(xt1);

    float m = __builtin_inff();
#pragma unroll
    for (int c = 0; c < CLS; ++c) {
        const float mtv = means_theta[c * CHW + e];
        const float lmv = lmm[c * CHW + e];
        const float y0  = xy_out[c * CHW2 + e];
        const float y1  = xy_out[c * CHW2 + CHW + e];
        const float dr  = fabsf(xt0 - mtv);
        const float da  = fabsf(lx - lmv);
        const float d0  = xx0 - y0, d1 = xx1 - y1;
        const float dist = w0sq * dr + w1sq * da + w2sq * (d0 * d0 + d1 * d1);
        m = fminf(m, dist);
    }
    out[idx] = m;
}

// ---------------------------------------------------------------------------
extern "C" void kernel_launch(void* const* d_in, const int* in_sizes, int n_in,
                              void* d_out, int out_size, void* d_ws, size_t ws_size,
                              hipStream_t stream)
{
    const float* x         = (const float*)d_in[0];
    const int*   labels    = (const int*)  d_in[1];
    const float* X_LEs     = (const float*)d_in[2];
    const float* X_LEs_xy  = (const float*)d_in[3];
    const float* X_weights = (const float*)d_in[4];
    const float* sigmas    = (const float*)d_in[5];
    const float* w1        = (const float*)d_in[6];
    const float* miu       = (const float*)d_in[7];
    const float* tao       = (const float*)d_in[8];
    const float* weight    = (const float*)d_in[9];

    float* ws          = (float*)d_ws;
    float* xle_out     = ws;                      // 524288 floats
    float* xy_out      = ws + 524288;             // 524288
    float* means_theta = ws + 1048576;            // 262144
    float* lmm         = ws + 1310720;            // 262144
    float* partials    = ws + 1572864;            // 8192 (8*16*64)
    float* lm0a        = ws + 1581056;            // 131072
    float* lm1a        = ws + 1712128;            // 131072
    float* lm1ea       = ws + 1843200;            // 131072 -> total 1974272 floats (7.9 MB)

    float* out  = (float*)d_out;       // 524288
    float* loss = out + Bn * CHW;      // 8

    hipLaunchKernelGGL(k1, dim3(2048 + DST * CHW / 256), dim3(256), 0, stream,
                       x, labels, X_LEs, X_LEs_xy, X_weights, miu,
                       xle_out, xy_out, lm0a, lm1a, lm1ea);
    hipLaunchKernelGGL(k2, dim3(CLS * KCHUNK), dim3(256), 0, stream,
                       xle_out, miu, sigmas, tao, w1, lm0a, lm1a, lm1ea,
                       means_theta, lmm, partials);
    hipLaunchKernelGGL(k3, dim3(Bn * CHW / 256 + 1), dim3(256), 0, stream,
                       x, weight, means_theta, lmm, xy_out,
                       labels, X_weights, sigmas, tao, partials,
                       out, loss);
}

// Round 4
// 95.814 us; speedup vs baseline: 2.3338x; 1.0117x over previous
//
#include <hip/hip_runtime.h>
#include <math.h>

#define EPSF 1e-6f
constexpr int Bn  = 32;
constexpr int CLS = 16;
constexpr int DST = 8;
constexpr int Cc  = 64, Hh = 16, Wd = 16;
constexpr int CHW  = Cc * Hh * Wd;   // 16384
constexpr int CHW2 = 2 * CHW;        // 32768
constexpr int CHW4 = 4 * CHW;        // 65536
constexpr int KCHUNK = 64;           // k2 chunks per class

// fast log-sigmoid: -log(1+exp(-x)) = min(x,0) - log(1+exp(-|x|))
__device__ __forceinline__ float fls(float x) {
    float t = __expf(-fabsf(x));
    return fminf(x, 0.0f) - __logf(1.0f + t);
}

__device__ __forceinline__ float4 ld4(const float* p) { return *(const float4*)p; }
__device__ __forceinline__ void st4(float* p, float4 v) { *(float4*)p = v; }

// ---------------------------------------------------------------------------
// k1: blocks [0,512):   kA — (class, e4-chunk) segment sums, float4.
//     blocks [512,640): lm-precompute — per (d,e4): log_sigmoid of miu, float4.
// ---------------------------------------------------------------------------
__global__ __launch_bounds__(256) void k1(
                   const float* __restrict__ x, const int* __restrict__ labels,
                   const float* __restrict__ X_LEs, const float* __restrict__ X_LEs_xy,
                   const float* __restrict__ X_weights, const float* __restrict__ miu,
                   float* __restrict__ xle_out, float* __restrict__ xy_out,
                   float* __restrict__ lm0a, float* __restrict__ lm1a,
                   float* __restrict__ lm1ea)
{
    if (blockIdx.x >= 512) {
        // ---- lm path: idx over [0, DST*CHW/4) ----
        const int idx = (blockIdx.x - 512) * 256 + threadIdx.x;   // [0, 32768)
        const int d  = idx >> 12;            // / 4096
        const int e4 = (idx & 4095) << 2;    // element offset, multiple of 4
        const float4 m0 = ld4(miu + d * CHW2 + e4);
        const float4 m1 = ld4(miu + d * CHW2 + CHW + e4);
        float4 r0, r1, r1e;
        r0.x = fls(m0.x); r0.y = fls(m0.y); r0.z = fls(m0.z); r0.w = fls(m0.w);
        r1.x = fls(m1.x); r1.y = fls(m1.y); r1.z = fls(m1.z); r1.w = fls(m1.w);
        r1e.x = fls(m1.x + EPSF); r1e.y = fls(m1.y + EPSF);
        r1e.z = fls(m1.z + EPSF); r1e.w = fls(m1.w + EPSF);
        st4(lm0a  + d * CHW + e4, r0);
        st4(lm1a  + d * CHW + e4, r1);
        st4(lm1ea + d * CHW + e4, r1e);
        return;
    }

    // ---- kA path: c = class (block-uniform), e4 over [0, CHW2) step 4 ----
    const int c  = blockIdx.x >> 5;                          // [0,16)
    const int t  = (blockIdx.x & 31) * 256 + threadIdx.x;    // [0, 8192)
    const int e4 = t << 2;                                   // [0, CHW2)

    __shared__ int lab_sh[Bn];
    if (threadIdx.x < Bn) lab_sh[threadIdx.x] = labels[threadIdx.x];
    __syncthreads();

    float4 acc_tm = {0.f,0.f,0.f,0.f}, acc_xy = {0.f,0.f,0.f,0.f};
    float cnt = 0.f;
    for (int b = 0; b < Bn; ++b) {
        if (lab_sh[b] == c) {            // block-uniform: skip loads entirely
            const float4 xt = ld4(x + b * CHW4 + e4);
            const float4 xx = ld4(x + b * CHW4 + CHW2 + e4);
            acc_tm.x += xt.x; acc_tm.y += xt.y; acc_tm.z += xt.z; acc_tm.w += xt.w;
            acc_xy.x += xx.x; acc_xy.y += xx.y; acc_xy.z += xx.z; acc_xy.w += xx.w;
            cnt += 1.0f;
        }
    }

    const float xw = X_weights[c] + cnt;
    const float4 le  = ld4(X_LEs    + c * CHW2 + e4);
    const float4 xy  = ld4(X_LEs_xy + c * CHW2 + e4);
    float4 o1, o2;
    o1.x = (le.x + acc_tm.x) / xw; o1.y = (le.y + acc_tm.y) / xw;
    o1.z = (le.z + acc_tm.z) / xw; o1.w = (le.w + acc_tm.w) / xw;
    o2.x = (xy.x + acc_xy.x) / xw; o2.y = (xy.y + acc_xy.y) / xw;
    o2.z = (xy.z + acc_xy.z) / xw; o2.w = (xy.w + acc_xy.w) / xw;
    st4(xle_out + c * CHW2 + e4, o1);
    st4(xy_out  + c * CHW2 + e4, o2);
}

// ---------------------------------------------------------------------------
// k2: per (c,e): means_theta, log(means_mag+eps); le_norm partials -> block
// reduce in LDS, write 8 unique partials per block. NO atomics. (unchanged)
// ---------------------------------------------------------------------------
__global__ __launch_bounds__(256) void k2(
                   const float* __restrict__ xle_out, const float* __restrict__ miu,
                   const float* __restrict__ sigmas, const float* __restrict__ tao,
                   const float* __restrict__ w1,
                   const float* __restrict__ lm0a, const float* __restrict__ lm1a,
                   const float* __restrict__ lm1ea,
                   float* __restrict__ means_theta, float* __restrict__ lmm_out,
                   float* __restrict__ partials)
{
    const int c     = blockIdx.x >> 6;
    const int chunk = blockIdx.x & 63;
    const int e     = chunk * blockDim.x + threadIdx.x;   // [0, CHW)

    const float sig    = sigmas[c];
    const float sig_sq = sig * sig;

    float w1sqv[DST];
    float ssum = 0.f;
#pragma unroll
    for (int d = 0; d < DST; ++d) { const float t = w1[d]; w1sqv[d] = t * t; ssum += t * t; }
    const float ssum_r = 1.0f / ssum;

    const float xle0 = xle_out[c * CHW2 + e];
    const float xle1 = xle_out[c * CHW2 + CHW + e];   // mag
    const float ls0  = fls(xle0);
    const float ls1  = fls(xle1);
    const float ls1e = fls(xle1 + EPSF);

    float mt = 0.f, mm = 0.f;
    float ln_d[DST];

#pragma unroll
    for (int d = 0; d < DST; ++d) {
        const float ta     = tao[d];
        const float tao_sq = ta * ta;
        const float den_r  = 1.0f / (sig_sq + tao_sq);
        const float a      = tao_sq * den_r;
        const float b      = sig_sq * den_r;
        const float wn     = w1sqv[d] * ssum_r;

        const float m0   = miu[d * CHW2 + e];
        const float lm0  = lm0a [d * CHW + e];
        const float lm1  = lm1a [d * CHW + e];
        const float lm1e = lm1ea[d * CHW + e];

        mt += (xle1 * a + m0 * b) * wn;
        mm += __expf((a * ls1e + b * lm1e) * wn);

        const float d0 = ls0 - lm0, d1 = ls1 - lm1;
        ln_d[d] = d0 * d0 + d1 * d1;
    }

    means_theta[c * CHW + e] = mt;
    lmm_out    [c * CHW + e] = __logf(mm + EPSF);

    __shared__ float sh[4][DST];
    const int wave = threadIdx.x >> 6;
    const int lane = threadIdx.x & 63;
#pragma unroll
    for (int d = 0; d < DST; ++d) {
        float v = ln_d[d];
        v += __shfl_down(v, 32);
        v += __shfl_down(v, 16);
        v += __shfl_down(v, 8);
        v += __shfl_down(v, 4);
        v += __shfl_down(v, 2);
        v += __shfl_down(v, 1);
        if (lane == 0) sh[wave][d] = v;
    }
    __syncthreads();
    if (threadIdx.x < DST) {
        const int d = threadIdx.x;
        const float s = sh[0][d] + sh[1][d] + sh[2][d] + sh[3][d];
        partials[(d * CLS + c) * KCHUNK + chunk] = s;
    }
}

// ---------------------------------------------------------------------------
// k3: blocks [0,512): kD float4 — dist over (c,b,e4), min over c.
//     block 512:      kC — loss[d], second-stage reduce of partials.
// ---------------------------------------------------------------------------
__global__ __launch_bounds__(256) void k3(
                   const float* __restrict__ x, const float* __restrict__ weight,
                   const float* __restrict__ means_theta, const float* __restrict__ lmm,
                   const float* __restrict__ xy_out,
                   const int* __restrict__ labels, const float* __restrict__ X_weights,
                   const float* __restrict__ sigmas, const float* __restrict__ tao,
                   const float* __restrict__ partials,
                   float* __restrict__ out, float* __restrict__ loss_out)
{
    if (blockIdx.x == 512) {
        const int t = threadIdx.x;
        if (t >= 128) return;
        const int d = t >> 4;
        const int c = t & 15;

        const float* p = partials + (d * CLS + c) * KCHUNK;
        float le = 0.f;
#pragma unroll
        for (int k = 0; k < KCHUNK; ++k) le += p[k];

        float cnt = 0.f;
        for (int b = 0; b < Bn; ++b) cnt += (labels[b] == c) ? 1.f : 0.f;
        const float xw = X_weights[c] + cnt;

        const float sig = sigmas[c], ssq = sig * sig;
        const float ta  = tao[d],    tsq = ta * ta;
        const float den = tsq + ssq;

        const float term1 = ssq / (den * den);
        const float term2 = ssq * le;
        const float term3 = (2.0f * (float)CHW) * (tsq * tsq - ssq * ssq) / xw;

        float v = term1 * (term2 + term3);
        v += __shfl_xor(v, 8);
        v += __shfl_xor(v, 4);
        v += __shfl_xor(v, 2);
        v += __shfl_xor(v, 1);
        if (c == 0) loss_out[d] = v * (1.0f / 16.0f);
        return;
    }

    const int idx = blockIdx.x * 256 + threadIdx.x;   // [0, 131072)
    const int b  = idx >> 12;                          // / 4096
    const int e4 = (idx & 4095) << 2;                  // [0, CHW) step 4

    const float w0 = weight[0], w1w = weight[1], w2 = weight[2];
    const float w0sq = w0 * w0, w1sq = w1w * w1w, w2sq = w2 * w2;

    const float* xb = x + b * CHW4;
    const float4 xt0 = ld4(xb + e4);
    const float4 xt1 = ld4(xb + CHW + e4);
    const float4 xx0 = ld4(xb + CHW2 + e4);
    const float4 xx1 = ld4(xb + CHW2 + CHW + e4);
    float4 lx;
    lx.x = __logf(xt1.x); lx.y = __logf(xt1.y);
    lx.z = __logf(xt1.z); lx.w = __logf(xt1.w);

    float4 m = { __builtin_inff(), __builtin_inff(), __builtin_inff(), __builtin_inff() };
#pragma unroll
    for (int c = 0; c < CLS; ++c) {
        const float4 mtv = ld4(means_theta + c * CHW + e4);
        const float4 lmv = ld4(lmm + c * CHW + e4);
        const float4 y0  = ld4(xy_out + c * CHW2 + e4);
        const float4 y1  = ld4(xy_out + c * CHW2 + CHW + e4);

        {
            const float dr = fabsf(xt0.x - mtv.x);
            const float da = fabsf(lx.x - lmv.x);
            const float d0 = xx0.x - y0.x, d1 = xx1.x - y1.x;
            m.x = fminf(m.x, w0sq * dr + w1sq * da + w2sq * (d0 * d0 + d1 * d1));
        }
        {
            const float dr = fabsf(xt0.y - mtv.y);
            const float da = fabsf(lx.y - lmv.y);
            const float d0 = xx0.y - y0.y, d1 = xx1.y - y1.y;
            m.y = fminf(m.y, w0sq * dr + w1sq * da + w2sq * (d0 * d0 + d1 * d1));
        }
        {
            const float dr = fabsf(xt0.z - mtv.z);
            const float da = fabsf(lx.z - lmv.z);
            const float d0 = xx0.z - y0.z, d1 = xx1.z - y1.z;
            m.z = fminf(m.z, w0sq * dr + w1sq * da + w2sq * (d0 * d0 + d1 * d1));
        }
        {
            const float dr = fabsf(xt0.w - mtv.w);
            const float da = fabsf(lx.w - lmv.w);
            const float d0 = xx0.w - y0.w, d1 = xx1.w - y1.w;
            m.w = fminf(m.w, w0sq * dr + w1sq * da + w2sq * (d0 * d0 + d1 * d1));
        }
    }
    st4(out + b * CHW + e4, m);
}

// ---------------------------------------------------------------------------
extern "C" void kernel_launch(void* const* d_in, const int* in_sizes, int n_in,
                              void* d_out, int out_size, void* d_ws, size_t ws_size,
                              hipStream_t stream)
{
    const float* x         = (const float*)d_in[0];
    const int*   labels    = (const int*)  d_in[1];
    const float* X_LEs     = (const float*)d_in[2];
    const float* X_LEs_xy  = (const float*)d_in[3];
    const float* X_weights = (const float*)d_in[4];
    const float* sigmas    = (const float*)d_in[5];
    const float* w1        = (const float*)d_in[6];
    const float* miu       = (const float*)d_in[7];
    const float* tao       = (const float*)d_in[8];
    const float* weight    = (const float*)d_in[9];

    float* ws          = (float*)d_ws;
    float* xle_out     = ws;                      // 524288 floats
    float* xy_out      = ws + 524288;             // 524288
    float* means_theta = ws + 1048576;            // 262144
    float* lmm         = ws + 1310720;            // 262144
    float* partials    = ws + 1572864;            // 8192 (8*16*64)
    float* lm0a        = ws + 1581056;            // 131072
    float* lm1a        = ws + 1712128;            // 131072
    float* lm1ea       = ws + 1843200;            // 131072

    float* out  = (float*)d_out;       // 524288
    float* loss = out + Bn * CHW;      // 8

    hipLaunchKernelGGL(k1, dim3(512 + 128), dim3(256), 0, stream,
                       x, labels, X_LEs, X_LEs_xy, X_weights, miu,
                       xle_out, xy_out, lm0a, lm1a, lm1ea);
    hipLaunchKernelGGL(k2, dim3(CLS * KCHUNK), dim3(256), 0, stream,
                       xle_out, miu, sigmas, tao, w1, lm0a, lm1a, lm1ea,
                       means_theta, lmm, partials);
    hipLaunchKernelGGL(k3, dim3(512 + 1), dim3(256), 0, stream,
                       x, weight, means_theta, lmm, xy_out,
                       labels, X_weights, sigmas, tao, partials,
                       out, loss);
}